// Round 1
// baseline (125.753 us; speedup 1.0000x reference)
//
#include <hip/hip_runtime.h>
#include <math.h>

#ifndef M_PI
#define M_PI 3.14159265358979323846
#endif

// Problem constants (fixed by the reference)
#define NPOLE 32     // N2
#define SLEN 2048    // L
#define NHALF 1024   // L/2

// One block per head h. 256 threads.
// Phase A: stage per-head params into LDS.
// Phase B: k_f[m] for m=0..1024 (Cauchy + Woodbury), double precision.
// Phase C: hermitian pack -> N=1024 complex Stockham IFFT in LDS -> store.
__global__ __launch_bounds__(256) void s4_nplr_kernel(
    const float* __restrict__ g_log_dt,
    const float* __restrict__ g_log_w_real,
    const float* __restrict__ g_w_imag,
    const float* __restrict__ g_B,
    const float* __restrict__ g_C,
    const float* __restrict__ g_P,
    float* __restrict__ g_out)
{
    const int h   = blockIdx.x;
    const int tid = threadIdx.x;

    __shared__ float2 sw[NPOLE];                       // w * dt
    __shared__ float2 sv00[NPOLE], sv01[NPOLE], sv10[NPOLE], sv11[NPOLE];
    __shared__ float2 bufA[NHALF];
    __shared__ float2 bufB[NHALF];
    __shared__ float2 s_kf_last;                       // k_f[1024] (Nyquist)

    const float dt_f = expf(g_log_dt[h]);

    if (tid < NPOLE) {
        const int n   = tid;
        const int idx = h * NPOLE + n;
        const float wre = -expf(g_log_w_real[idx]) * dt_f;
        const float wim = g_w_imag[idx] * dt_f;
        sw[n] = make_float2(wre, wim);
        const float Br = g_B[2*idx+0], Bi = g_B[2*idx+1];
        const float Cr = g_C[2*idx+0], Ci = g_C[2*idx+1];
        const float Pr = g_P[2*idx+0], Pi = g_P[2*idx+1];
        // v00 = B*C ; v01 = B*conj(P) ; v10 = P*C ; v11 = |P|^2
        sv00[n] = make_float2(Br*Cr - Bi*Ci, Br*Ci + Bi*Cr);
        sv01[n] = make_float2(Br*Pr + Bi*Pi, Bi*Pr - Br*Pi);
        sv10[n] = make_float2(Pr*Cr - Pi*Ci, Pr*Ci + Pi*Cr);
        sv11[n] = make_float2(Pr*Pr + Pi*Pi, 0.0f);
    }
    __syncthreads();

    const double dt = (double)dt_f;

    // ---- Phase B: Cauchy + Woodbury per spectral node m ----
    for (int m = tid; m <= NHALF; m += 256) {
        // omega = exp(-2*pi*i*m/L); theta = -pi*m/1024
        double theta = -(M_PI / (double)NHALF) * (double)m;
        double si, co;
        sincos(theta, &si, &co);
        double dr = 1.0 + co, di = si;           // 1 + omega
        double d2 = dr*dr + di*di;
        double invd2 = 1.0 / d2;
        double nr = 1.0 - co, ni = -si;          // 1 - omega
        // z = 2*(1-omega)/(1+omega)
        double zr = 2.0 * (nr*dr + ni*di) * invd2;
        double zi = 2.0 * (ni*dr - nr*di) * invd2;

        double r00r=0.0, r00i=0.0, r01r=0.0, r01i=0.0;
        double r10r=0.0, r10i=0.0, r11r=0.0, r11i=0.0;

        for (int n = 0; n < NPOLE; ++n) {
            float2 wv = sw[n];                    // wave-uniform LDS broadcast
            double ar  = zr - (double)wv.x;       // Re(z - w) == Re(z - conj(w))
            double aim = zi - (double)wv.y;       // Im(z - w)
            double aip = zi + (double)wv.y;       // Im(z - conj(w))
            double inv1 = 1.0 / (ar*ar + aim*aim);
            double inv2 = 1.0 / (ar*ar + aip*aip);
            double d1r = ar*inv1,  d1i = -aim*inv1;   // 1/(z - w)
            double e2r = ar*inv2,  e2i = -aip*inv2;   // 1/(z - conj(w))
            // term_ab = v*d1 + conj(v)*e2
            double Sr = d1r + e2r;
            double Dr = d1r - e2r;
            double Si = d1i + e2i;
            double Di = e2i - d1i;
            float2 v;
            v = sv00[n]; r00r += v.x*Sr + v.y*Di; r00i += v.x*Si + v.y*Dr;
            v = sv01[n]; r01r += v.x*Sr + v.y*Di; r01i += v.x*Si + v.y*Dr;
            v = sv10[n]; r10r += v.x*Sr + v.y*Di; r10i += v.x*Si + v.y*Dr;
            v = sv11[n]; r11r += v.x*Sr + v.y*Di; r11i += v.x*Si + v.y*Dr;
        }
        r00r*=dt; r00i*=dt; r01r*=dt; r01i*=dt;
        r10r*=dt; r10i*=dt; r11r*=dt; r11i*=dt;

        // k_f = (r00 - r01*r10/(1+r11)) * 2/(1+omega)
        double wdr = 1.0 + r11r, wdi = r11i;
        double winv = 1.0 / (wdr*wdr + wdi*wdi);
        double tr = r01r*r10r - r01i*r10i;
        double ti = r01r*r10i + r01i*r10r;
        double cr = (tr*wdr + ti*wdi) * winv;
        double ci = (ti*wdr - tr*wdi) * winv;
        double kr = r00r - cr;
        double ki = r00i - ci;
        double fr =  2.0 * dr * invd2;            // 2/(1+omega)
        double fi = -2.0 * di * invd2;
        double outr = kr*fr - ki*fi;
        double outi = kr*fi + ki*fr;

        if (m < NHALF) bufA[m] = make_float2((float)outr, (float)outi);
        else           s_kf_last = make_float2((float)outr, (float)outi);
    }
    __syncthreads();

    // ---- Phase C1: hermitian pack X[0..1024] -> Y[0..1023] in bufB ----
    // E[m] = (X[m] + conj(X[N-m]))/2 ; O[m] = e^{+2pi i m/L} (X[m]-conj(X[N-m]))/2
    // Y = E + i*O ; y = IFFT_N(Y) ; x[2l]=Re y[l], x[2l+1]=Im y[l]
    for (int l = tid; l < NHALF; l += 256) {
        float2 Xm = bufA[l];
        float2 Xn = (l == 0) ? s_kf_last : bufA[NHALF - l];
        if (l == 0) { Xm.y = 0.0f; Xn.y = 0.0f; }   // numpy C2R ignores DC/Nyquist imag
        float er  = 0.5f*(Xm.x + Xn.x);
        float ei  = 0.5f*(Xm.y - Xn.y);
        float odr = 0.5f*(Xm.x - Xn.x);
        float odi = 0.5f*(Xm.y + Xn.y);
        float ang = (float)(M_PI/1024.0) * (float)l;  // +2*pi*l/L
        float sn, cs;
        sincosf(ang, &sn, &cs);
        float Or = odr*cs - odi*sn;
        float Oi = odr*sn + odi*cs;
        bufB[l] = make_float2(er - Oi, ei + Or);
    }
    __syncthreads();

    // ---- Phase C2: Stockham radix-2 inverse FFT, N=1024, 10 stages ----
    float2* src = bufB;
    float2* dst = bufA;
    int s = 1;
    for (int t = 0; t < 10; ++t) {
        #pragma unroll
        for (int j = 0; j < 2; ++j) {
            const int i    = tid + (j << 8);      // 0..511
            const int lo   = i & (s - 1);         // q
            const int base = i - lo;              // s*p
            float ang = (float)(M_PI/512.0) * (float)base;  // +2*pi*p/n_t
            float sn, cs;
            sincosf(ang, &sn, &cs);
            float2 a = src[i];
            float2 b = src[i + 512];
            float2 sum = make_float2(a.x + b.x, a.y + b.y);
            float2 dif = make_float2(a.x - b.x, a.y - b.y);
            float2 tw  = make_float2(dif.x*cs - dif.y*sn, dif.x*sn + dif.y*cs);
            const int o = base*2 + lo;
            dst[o]     = sum;
            dst[o + s] = tw;
        }
        __syncthreads();
        float2* tmp = src; src = dst; dst = tmp;
        s <<= 1;
    }
    // after an even number of swaps the result sits in `src`

    // ---- store: x[2l] = Re(y[l])/N, x[2l+1] = Im(y[l])/N ----
    const float scale = 1.0f / (float)NHALF;
    float2* outp = (float2*)(g_out + (size_t)h * SLEN);
    for (int l = tid; l < NHALF; l += 256) {
        float2 y = src[l];
        outp[l] = make_float2(y.x * scale, y.y * scale);
    }
}

extern "C" void kernel_launch(void* const* d_in, const int* in_sizes, int n_in,
                              void* d_out, int out_size, void* d_ws, size_t ws_size,
                              hipStream_t stream) {
    const float* log_dt     = (const float*)d_in[0];
    const float* log_w_real = (const float*)d_in[1];
    const float* w_imag     = (const float*)d_in[2];
    const float* B          = (const float*)d_in[3];
    const float* C          = (const float*)d_in[4];
    const float* P          = (const float*)d_in[5];
    float* out = (float*)d_out;
    const int H = in_sizes[0];   // 512
    s4_nplr_kernel<<<H, 256, 0, stream>>>(log_dt, log_w_real, w_imag, B, C, P, out);
}

// Round 2
// 83.705 us; speedup vs baseline: 1.5023x; 1.5023x over previous
//
#include <hip/hip_runtime.h>
#include <math.h>

#ifndef M_PI
#define M_PI 3.14159265358979323846
#endif

#define NPOLE 32     // N2
#define SLEN 2048    // L
#define NHALF 1024   // L/2

// One block (512 threads) per head h.
// Key analytic facts (omega on unit circle):
//   z      = 2(1-omega)/(1+omega) = 2i * tan(pi*m/L)   (purely imaginary!)
//   2/(1+omega)                   = 1 + i*tan(pi*m/L)
// so the Cauchy denominators have a constant real part per pole: -Re(w)*dt.
// Everything runs in fp32 with raw v_rcp_f32 (error budget ~1e-7 rel, no
// cancellation paths: Re(1+r11) >= 1 always since Re(-w)>0).
// Nyquist m=1024 uses t=1e8 which converges to the exact limit dt*sum(Re v00).
__global__ __launch_bounds__(512) void s4_nplr_kernel(
    const float* __restrict__ g_log_dt,
    const float* __restrict__ g_log_w_real,
    const float* __restrict__ g_w_imag,
    const float* __restrict__ g_B,
    const float* __restrict__ g_C,
    const float* __restrict__ g_P,
    float* __restrict__ g_out)
{
    const int h   = blockIdx.x;
    const int tid = threadIdx.x;

    __shared__ float4 spole[NPOLE];   // {ar, ar2, wim_dt, 0}  ar = -Re(w)*dt > 0
    __shared__ float4 sva[NPOLE];     // dt * {v00r, v00i, v01r, v01i}
    __shared__ float4 svb[NPOLE];     // dt * {v10r, v10i, v11r, 0}
    __shared__ float2 bufA[NHALF];
    __shared__ float2 bufB[NHALF];
    __shared__ float2 stw[512];       // FFT twiddles e^{i*pi*k/512}
    __shared__ float2 s_kf_last;      // k_f[1024]

    const float dt = expf(g_log_dt[h]);

    if (tid < NPOLE) {
        const int n   = tid;
        const int idx = h * NPOLE + n;
        const float ar  = expf(g_log_w_real[idx]) * dt;   // -Re(w)*dt
        const float wim = g_w_imag[idx] * dt;
        spole[n] = make_float4(ar, ar * ar, wim, 0.0f);
        const float Br = g_B[2*idx+0], Bi = g_B[2*idx+1];
        const float Cr = g_C[2*idx+0], Ci = g_C[2*idx+1];
        const float Pr = g_P[2*idx+0], Pi = g_P[2*idx+1];
        // v00=B*C, v01=B*conj(P), v10=P*C, v11=|P|^2 ; dt folded in
        sva[n] = make_float4(dt*(Br*Cr - Bi*Ci), dt*(Br*Ci + Bi*Cr),
                             dt*(Br*Pr + Bi*Pi), dt*(Bi*Pr - Br*Pi));
        svb[n] = make_float4(dt*(Pr*Cr - Pi*Ci), dt*(Pr*Ci + Pi*Cr),
                             dt*(Pr*Pr + Pi*Pi), 0.0f);
    }
    // FFT twiddle table: stw[k] = exp(+i*pi*k/512)
    {
        float ang = (float)(M_PI / 512.0) * (float)tid;
        float sn, cs;
        sincosf(ang, &sn, &cs);
        stw[tid] = make_float2(cs, sn);
    }
    __syncthreads();

    // ---- Phase B: two m-nodes per thread, shared pole loads ----
    {
        const int mA = tid;          // 0..511
        const int mB = tid + 512;    // 512..1023
        const float tA = tanf((float)mA * (float)(M_PI / 2048.0));
        const float tB = tanf((float)mB * (float)(M_PI / 2048.0));
        const float t2A = tA + tA, t2B = tB + tB;

        float a00r=0.f,a00i=0.f,a01r=0.f,a01i=0.f,a10r=0.f,a10i=0.f,a11r=0.f,a11i=0.f;
        float b00r=0.f,b00i=0.f,b01r=0.f,b01i=0.f,b10r=0.f,b10i=0.f,b11r=0.f,b11i=0.f;

        #pragma unroll 4
        for (int n = 0; n < NPOLE; ++n) {
            const float4 pa = spole[n];   // broadcast LDS reads
            const float4 va = sva[n];
            const float4 vb = svb[n];
            // node A
            {
                float aim = t2A - pa.z, aip = t2A + pa.z;
                float inv1 = __builtin_amdgcn_rcpf(fmaf(aim, aim, pa.y));
                float inv2 = __builtin_amdgcn_rcpf(fmaf(aip, aip, pa.y));
                float d1r = pa.x * inv1, e2r = pa.x * inv2;
                float d1i = -aim * inv1, e2i = -aip * inv2;
                float Sr = d1r + e2r, Dr = d1r - e2r;
                float Si = d1i + e2i, Di = e2i - d1i;
                a00r = fmaf(va.x, Sr, fmaf(va.y, Di, a00r));
                a00i = fmaf(va.x, Si, fmaf(va.y, Dr, a00i));
                a01r = fmaf(va.z, Sr, fmaf(va.w, Di, a01r));
                a01i = fmaf(va.z, Si, fmaf(va.w, Dr, a01i));
                a10r = fmaf(vb.x, Sr, fmaf(vb.y, Di, a10r));
                a10i = fmaf(vb.x, Si, fmaf(vb.y, Dr, a10i));
                a11r = fmaf(vb.z, Sr, a11r);
                a11i = fmaf(vb.z, Si, a11i);
            }
            // node B
            {
                float aim = t2B - pa.z, aip = t2B + pa.z;
                float inv1 = __builtin_amdgcn_rcpf(fmaf(aim, aim, pa.y));
                float inv2 = __builtin_amdgcn_rcpf(fmaf(aip, aip, pa.y));
                float d1r = pa.x * inv1, e2r = pa.x * inv2;
                float d1i = -aim * inv1, e2i = -aip * inv2;
                float Sr = d1r + e2r, Dr = d1r - e2r;
                float Si = d1i + e2i, Di = e2i - d1i;
                b00r = fmaf(va.x, Sr, fmaf(va.y, Di, b00r));
                b00i = fmaf(va.x, Si, fmaf(va.y, Dr, b00i));
                b01r = fmaf(va.z, Sr, fmaf(va.w, Di, b01r));
                b01i = fmaf(va.z, Si, fmaf(va.w, Dr, b01i));
                b10r = fmaf(vb.x, Sr, fmaf(vb.y, Di, b10r));
                b10i = fmaf(vb.x, Si, fmaf(vb.y, Dr, b10i));
                b11r = fmaf(vb.z, Sr, b11r);
                b11i = fmaf(vb.z, Si, b11i);
            }
        }

        // Woodbury + spectral factor (1 + i*t), node A
        {
            float wdr = 1.0f + a11r, wdi = a11i;
            float winv = __builtin_amdgcn_rcpf(fmaf(wdr, wdr, wdi*wdi));
            float trm = a01r*a10r - a01i*a10i;
            float tim = a01r*a10i + a01i*a10r;
            float cr = (trm*wdr + tim*wdi) * winv;
            float ci = (tim*wdr - trm*wdi) * winv;
            float kr = a00r - cr, ki = a00i - ci;
            bufA[mA] = make_float2(fmaf(-ki, tA, kr), fmaf(kr, tA, ki));
        }
        // node B
        {
            float wdr = 1.0f + b11r, wdi = b11i;
            float winv = __builtin_amdgcn_rcpf(fmaf(wdr, wdr, wdi*wdi));
            float trm = b01r*b10r - b01i*b10i;
            float tim = b01r*b10i + b01i*b10r;
            float cr = (trm*wdr + tim*wdi) * winv;
            float ci = (tim*wdr - trm*wdi) * winv;
            float kr = b00r - cr, ki = b00i - ci;
            bufA[mB] = make_float2(fmaf(-ki, tB, kr), fmaf(kr, tB, ki));
        }
    }
    // Nyquist m=1024: exact limit k_f = dt * sum_n Re(v00_n)  (imag ignored by C2R)
    if (tid == 0) {
        float s = 0.0f;
        #pragma unroll
        for (int n = 0; n < NPOLE; ++n) s += sva[n].x;
        s_kf_last = make_float2(s, 0.0f);
    }
    __syncthreads();

    // ---- Phase C1: hermitian pack X[0..1024] -> Y[0..1023] in bufB ----
    for (int l = tid; l < NHALF; l += 512) {
        float2 Xm = bufA[l];
        float2 Xn = (l == 0) ? s_kf_last : bufA[NHALF - l];
        if (l == 0) { Xm.y = 0.0f; Xn.y = 0.0f; }   // numpy C2R: DC/Nyquist imag ignored
        float er  = 0.5f*(Xm.x + Xn.x);
        float ei  = 0.5f*(Xm.y - Xn.y);
        float odr = 0.5f*(Xm.x - Xn.x);
        float odi = 0.5f*(Xm.y + Xn.y);
        float ang = (float)(M_PI/1024.0) * (float)l;  // +2*pi*l/L
        float sn, cs;
        sincosf(ang, &sn, &cs);
        float Or = odr*cs - odi*sn;
        float Oi = odr*sn + odi*cs;
        bufB[l] = make_float2(er - Oi, ei + Or);
    }
    __syncthreads();

    // ---- Phase C2: Stockham radix-2 inverse FFT, N=1024, 10 stages ----
    float2* src = bufB;
    float2* dst = bufA;
    int s = 1;
    for (int t = 0; t < 10; ++t) {
        const int i    = tid;                 // 0..511
        const int lo   = i & (s - 1);
        const int base = i - lo;              // s*p in [0,512), indexes stw directly
        float2 twf = stw[base];
        float2 a = src[i];
        float2 b = src[i + 512];
        float2 sum = make_float2(a.x + b.x, a.y + b.y);
        float2 dif = make_float2(a.x - b.x, a.y - b.y);
        float2 tw  = make_float2(dif.x*twf.x - dif.y*twf.y,
                                 dif.x*twf.y + dif.y*twf.x);
        const int o = base*2 + lo;
        dst[o]     = sum;
        dst[o + s] = tw;
        __syncthreads();
        float2* tmp = src; src = dst; dst = tmp;
        s <<= 1;
    }
    // after 10 swaps the result sits in `src` (== bufB)

    // ---- store: x[2l] = Re(y[l])/N, x[2l+1] = Im(y[l])/N ; float4 per thread ----
    const float scale = 1.0f / (float)NHALF;
    float4* outp = (float4*)(g_out + (size_t)h * SLEN);
    {
        const float4 y2 = *((const float4*)&src[2*tid]);
        outp[tid] = make_float4(y2.x*scale, y2.y*scale, y2.z*scale, y2.w*scale);
    }
}

extern "C" void kernel_launch(void* const* d_in, const int* in_sizes, int n_in,
                              void* d_out, int out_size, void* d_ws, size_t ws_size,
                              hipStream_t stream) {
    const float* log_dt     = (const float*)d_in[0];
    const float* log_w_real = (const float*)d_in[1];
    const float* w_imag     = (const float*)d_in[2];
    const float* B          = (const float*)d_in[3];
    const float* C          = (const float*)d_in[4];
    const float* P          = (const float*)d_in[5];
    float* out = (float*)d_out;
    const int H = in_sizes[0];   // 512
    s4_nplr_kernel<<<H, 512, 0, stream>>>(log_dt, log_w_real, w_imag, B, C, P, out);
}